// Round 1
// baseline (7111.936 us; speedup 1.0000x reference)
//
#include <hip/hip_runtime.h>

#define MFMA16 __builtin_amdgcn_mfma_f32_16x16x32_bf16

typedef __attribute__((ext_vector_type(8))) short short8;
typedef __attribute__((ext_vector_type(4))) float floatx4;

static constexpr int T_STEPS = 50;
static constexpr int BATCH   = 1024;
static constexpr int SDIM    = 32;
static constexpr int DDIM    = 600;
static constexpr int ADIM    = 6;
static constexpr int KP      = 608;   // padded K/N per gate
static constexpr int PITCH   = 616;   // LDS row pitch (shorts): mult of 8 (16B align), 20 mod 32 -> <=2-way bank conflict (free)
static constexpr int SAPITCH = 72;

// workspace layout (ushort offsets)
static constexpr size_t SZ608    = (size_t)608 * 608;
static constexpr size_t OFF_WIHR = 0;
static constexpr size_t OFF_WIHZ = OFF_WIHR + SZ608;
static constexpr size_t OFF_WIHN = OFF_WIHZ + SZ608;
static constexpr size_t OFF_WHHR = OFF_WIHN + SZ608;
static constexpr size_t OFF_WHHZ = OFF_WHHR + SZ608;
static constexpr size_t OFF_WHHN = OFF_WHHZ + SZ608;
static constexpr size_t OFF_WP1  = OFF_WHHN + SZ608;
static constexpr size_t OFF_WQ1D = OFF_WP1  + SZ608;
static constexpr size_t OFF_WQ1E = OFF_WQ1D + SZ608;              // [608][1024]
static constexpr size_t OFF_WSA  = OFF_WQ1E + (size_t)608 * 1024; // [608][64]
static constexpr size_t OFF_WHEAD= OFF_WSA  + (size_t)608 * 64;   // [128][608]
static constexpr size_t OFF_PREQ = OFF_WHEAD+ (size_t)128 * 608;  // [50*1024][600] bf16

// output offsets (fp32 elements), reference return order
static constexpr size_t O_PM = 0;
static constexpr size_t O_PS = 1638400;
static constexpr size_t O_PR = 3276800;
static constexpr size_t O_D1 = 4915200;
static constexpr size_t O_QM = 35635200;
static constexpr size_t O_QS = 37273600;
static constexpr size_t O_PO = 38912000;
static constexpr size_t O_D2 = 40550400;

__device__ __forceinline__ unsigned short f2bf(float f) {
  unsigned u = __float_as_uint(f);
  u += 0x7FFFu + ((u >> 16) & 1u);   // RNE
  return (unsigned short)(u >> 16);
}
__device__ __forceinline__ float bf2f(unsigned short u) {
  return __uint_as_float(((unsigned)u) << 16);
}
__device__ __forceinline__ float elu_f(float v) { return v > 0.f ? v : expm1f(v); }
__device__ __forceinline__ float sigmoid_f(float x) { return 1.f / (1.f + expf(-x)); }
__device__ __forceinline__ float tanh_f(float x) {
  x = fminf(fmaxf(x, -15.f), 15.f);
  float e = expf(2.f * x);
  return (e - 1.f) / (e + 1.f);
}

// ---------------- prep: stage weights as bf16, padded/split per gate ----------------
__global__ __launch_bounds__(256) void stage_weights(
    const float* __restrict__ Win, const float* __restrict__ Wih, const float* __restrict__ Whh,
    const float* __restrict__ Wp1, const float* __restrict__ Wq1,
    const float* __restrict__ Wp2, const float* __restrict__ Wq2,
    unsigned short* __restrict__ ws)
{
  const int region = blockIdx.y;
  int R = 608, C = 608;
  size_t dst = 0;
  switch (region) {
    case 0: dst = OFF_WIHR; break;
    case 1: dst = OFF_WIHZ; break;
    case 2: dst = OFF_WIHN; break;
    case 3: dst = OFF_WHHR; break;
    case 4: dst = OFF_WHHZ; break;
    case 5: dst = OFF_WHHN; break;
    case 6: dst = OFF_WP1;  break;
    case 7: dst = OFF_WQ1D; break;
    case 8: dst = OFF_WQ1E; C = 1024; break;
    case 9: dst = OFF_WSA;  C = 64;   break;
    case 10: dst = OFF_WHEAD; R = 128; break;
  }
  const int total = R * C;
  for (int e = blockIdx.x * 256 + threadIdx.x; e < total; e += gridDim.x * 256) {
    int n = e / C, k = e - n * C;
    float v = 0.f;
    switch (region) {
      case 0: if (n < 600 && k < 600) v = Wih[(size_t)n * 600 + k]; break;
      case 1: if (n < 600 && k < 600) v = Wih[(size_t)(600 + n) * 600 + k]; break;
      case 2: if (n < 600 && k < 600) v = Wih[(size_t)(1200 + n) * 600 + k]; break;
      case 3: if (n < 600 && k < 600) v = Whh[(size_t)n * 600 + k]; break;
      case 4: if (n < 600 && k < 600) v = Whh[(size_t)(600 + n) * 600 + k]; break;
      case 5: if (n < 600 && k < 600) v = Whh[(size_t)(1200 + n) * 600 + k]; break;
      case 6: if (n < 600 && k < 600) v = Wp1[(size_t)n * 600 + k]; break;
      case 7: if (n < 600 && k < 600) v = Wq1[(size_t)n * 1624 + k]; break;
      case 8: if (n < 600) v = Wq1[(size_t)n * 1624 + 600 + k]; break;
      case 9: if (n < 600) { if (k < 32) v = Win[(size_t)n * 38 + 6 + k];
                             else if (k < 38) v = Win[(size_t)n * 38 + (k - 32)]; } break;
      case 10: if (k < 600) v = (n < 64) ? Wp2[(size_t)n * 600 + k]
                                         : Wq2[(size_t)(n - 64) * 600 + k]; break;
    }
    ws[dst + (size_t)e] = f2bf(v);
  }
}

// ---------------- prep: pre_q[t,b,:] = enc[t,b,:] @ Wq1[:,600:].T + bq1 (bf16 out) ----------------
__global__ __launch_bounds__(256) void preq_gemm(
    const float* __restrict__ enc, const float* __restrict__ bq1,
    const unsigned short* __restrict__ ws, unsigned short* __restrict__ preq)
{
  __shared__ unsigned short A[16 * 1032];  // pitch 1032: 16B aligned, 2-way conflicts only
  const size_t g0 = (size_t)blockIdx.x * 16;
  const int tid = threadIdx.x;

  const float4* e4 = (const float4*)(enc + g0 * 1024);
  for (int i = tid; i < 16 * 256; i += 256) {
    int row = i >> 8, c4 = i & 255;
    float4 v = e4[row * 256 + c4];
    int base = row * 1032 + c4 * 4;
    A[base + 0] = f2bf(v.x); A[base + 1] = f2bf(v.y);
    A[base + 2] = f2bf(v.z); A[base + 3] = f2bf(v.w);
  }
  __syncthreads();

  const int wave = tid >> 6, lane = tid & 63, q = lane >> 4, l15 = lane & 15;
  const unsigned short* Wq1e = ws + OFF_WQ1E;
  for (int tile = wave; tile < 38; tile += 4) {
    const int n0 = tile * 16;
    floatx4 acc = {0.f, 0.f, 0.f, 0.f};
    const unsigned short* wb = Wq1e + (size_t)(n0 + l15) * 1024 + q * 8;
    const int aoff = l15 * 1032 + q * 8;
    for (int ki = 0; ki < 32; ++ki) {
      short8 a = *(const short8*)(&A[aoff + ki * 32]);
      short8 b = *(const short8*)(wb + ki * 32);
      acc = MFMA16(a, b, acc, 0, 0, 0);
    }
    const int col = n0 + l15;
    if (col < 600) {
      float bb = bq1[col];
      for (int i = 0; i < 4; ++i) {
        int row = q * 4 + i;
        preq[(g0 + row) * 600 + col] = f2bf(acc[i] + bb);
      }
    }
  }
}

// ---------------- main persistent rollout: 64 wgs x 16 batch rows, zero grid syncs ----------------
__global__ __launch_bounds__(1024) void rssm_rollout(
    const float* __restrict__ actions, const float* __restrict__ init_stoch,
    const float* __restrict__ init_det,
    const float* __restrict__ eps_p, const float* __restrict__ eps_q,
    const float* __restrict__ b_in, const float* __restrict__ b_ih, const float* __restrict__ b_hh,
    const float* __restrict__ bp1, const float* __restrict__ bp2, const float* __restrict__ bq2,
    const unsigned short* __restrict__ ws, float* __restrict__ out)
{
  __shared__ unsigned short sm[3 * 16 * PITCH + 16 * SAPITCH];  // 61,440 B
  unsigned short* DB0 = sm;
  unsigned short* DB1 = sm + 16 * PITCH;
  unsigned short* XB  = sm + 2 * 16 * PITCH;   // rnn_in, later h_p
  unsigned short* SA  = sm + 3 * 16 * PITCH;   // [stoch(32)|act(6)|pad] bf16

  const int tid  = threadIdx.x;
  const int wave = tid >> 6, lane = tid & 63, q = lane >> 4, l15 = lane & 15;
  const int brow0 = blockIdx.x * 16;

  const unsigned short* preq = ws + OFF_PREQ;
  float* out_pm = out + O_PM; float* out_ps = out + O_PS; float* out_pr = out + O_PR;
  float* out_d1 = out + O_D1; float* out_qm = out + O_QM; float* out_qs = out + O_QS;
  float* out_po = out + O_PO; float* out_d2 = out + O_D2;

  for (int t = 0; t < T_STEPS; ++t) {
    unsigned short* Dold = (t & 1) ? DB1 : DB0;
    unsigned short* Dnew = (t & 1) ? DB0 : DB1;
    unsigned short* Hq   = Dold;   // safe: Dold dead after P1, rewritten next step's P1

    // ---- P0a: init (t=0) + stage act[t] into SA
    if (t == 0) {
      for (int i = tid; i < 3 * 16 * PITCH + 16 * SAPITCH; i += 1024) sm[i] = 0;
      __syncthreads();
      for (int i = tid; i < 16 * SDIM; i += 1024) {
        int r = i >> 5, c = i & 31;
        SA[r * SAPITCH + c] = f2bf(init_stoch[(size_t)(brow0 + r) * SDIM + c]);
      }
      for (int i = tid; i < 16 * DDIM; i += 1024) {
        int r = i / DDIM, k = i - r * DDIM;
        DB0[r * PITCH + k] = f2bf(init_det[(size_t)(brow0 + r) * DDIM + k]);
      }
    }
    if (tid < 96) {
      int r = tid / 6, j = tid - r * 6;
      SA[r * SAPITCH + 32 + j] = f2bf(actions[((size_t)t * BATCH + brow0 + r) * ADIM + j]);
    }
    __syncthreads();

    // ---- P0b: rnn_in = elu([stoch|act] @ Wsa.T + b_in) -> XB (bf16)
    for (int tile = wave; tile < 38; tile += 16) {
      const int n0 = tile * 16;
      floatx4 acc = {0.f, 0.f, 0.f, 0.f};
      const unsigned short* wb = ws + OFF_WSA + (size_t)(n0 + l15) * 64 + q * 8;
      const int aoff = l15 * SAPITCH + q * 8;
      short8 a0 = *(const short8*)(&SA[aoff]);
      short8 bv0 = *(const short8*)(wb);
      acc = MFMA16(a0, bv0, acc, 0, 0, 0);
      short8 a1 = *(const short8*)(&SA[aoff + 32]);
      short8 bv1 = *(const short8*)(wb + 32);
      acc = MFMA16(a1, bv1, acc, 0, 0, 0);
      const int col = n0 + l15;
      if (col < DDIM) {
        float bi = b_in[col];
        for (int i = 0; i < 4; ++i)
          XB[(q * 4 + i) * PITCH + col] = f2bf(elu_f(acc[i] + bi));
      }
    }
    __syncthreads();

    // ---- P1: GRU (gates fused in-register), det_new -> Dnew + outputs 3,7
    for (int tile = wave; tile < 38; tile += 16) {
      const int n0 = tile * 16;
      floatx4 aIr = {0,0,0,0}, aIz = {0,0,0,0}, aIn = {0,0,0,0};
      floatx4 aHr = {0,0,0,0}, aHz = {0,0,0,0}, aHn = {0,0,0,0};
      const size_t wrow = (size_t)(n0 + l15) * KP + q * 8;
      const unsigned short* pIr = ws + OFF_WIHR + wrow;
      const unsigned short* pIz = ws + OFF_WIHZ + wrow;
      const unsigned short* pIn = ws + OFF_WIHN + wrow;
      const unsigned short* pHr = ws + OFF_WHHR + wrow;
      const unsigned short* pHz = ws + OFF_WHHZ + wrow;
      const unsigned short* pHn = ws + OFF_WHHN + wrow;
      const int aoff = l15 * PITCH + q * 8;
      for (int ki = 0; ki < 19; ++ki) {
        short8 ax = *(const short8*)(&XB[aoff + ki * 32]);
        short8 ad = *(const short8*)(&Dold[aoff + ki * 32]);
        short8 bIr = *(const short8*)(pIr + ki * 32);
        short8 bIz = *(const short8*)(pIz + ki * 32);
        short8 bIn = *(const short8*)(pIn + ki * 32);
        short8 bHr = *(const short8*)(pHr + ki * 32);
        short8 bHz = *(const short8*)(pHz + ki * 32);
        short8 bHn = *(const short8*)(pHn + ki * 32);
        aIr = MFMA16(ax, bIr, aIr, 0, 0, 0);
        aIz = MFMA16(ax, bIz, aIz, 0, 0, 0);
        aIn = MFMA16(ax, bIn, aIn, 0, 0, 0);
        aHr = MFMA16(ad, bHr, aHr, 0, 0, 0);
        aHz = MFMA16(ad, bHz, aHz, 0, 0, 0);
        aHn = MFMA16(ad, bHn, aHn, 0, 0, 0);
      }
      const int d = n0 + l15;
      if (d < DDIM) {
        float bihr = b_ih[d],        bhhr = b_hh[d];
        float bihz = b_ih[600 + d],  bhhz = b_hh[600 + d];
        float bihn = b_ih[1200 + d], bhhn = b_hh[1200 + d];
        for (int i = 0; i < 4; ++i) {
          int row = q * 4 + i;
          float r = sigmoid_f(aIr[i] + aHr[i] + bihr + bhhr);
          float z = sigmoid_f(aIz[i] + aHz[i] + bihz + bhhz);
          float n = tanh_f(aIn[i] + bihn + r * (aHn[i] + bhhn));
          float dprev = bf2f(Dold[row * PITCH + d]);
          float dn = (1.f - z) * n + z * dprev;
          Dnew[row * PITCH + d] = f2bf(dn);
          size_t oidx = ((size_t)t * BATCH + brow0 + row) * DDIM + d;
          out_d1[oidx] = dn;
          out_d2[oidx] = dn;
        }
      }
    }
    __syncthreads();

    // ---- P2: h_p = elu(det@Wp1.T + bp1) -> XB ; h_q = elu(det@Wq1d.T + preq) -> Hq
    for (int tile = wave; tile < 38; tile += 16) {
      const int n0 = tile * 16;
      floatx4 accP = {0,0,0,0}, accQ = {0,0,0,0};
      const size_t wrow = (size_t)(n0 + l15) * KP + q * 8;
      const unsigned short* pP = ws + OFF_WP1  + wrow;
      const unsigned short* pQ = ws + OFF_WQ1D + wrow;
      const int aoff = l15 * PITCH + q * 8;
      for (int ki = 0; ki < 19; ++ki) {
        short8 a = *(const short8*)(&Dnew[aoff + ki * 32]);
        short8 bp = *(const short8*)(pP + ki * 32);
        short8 bq = *(const short8*)(pQ + ki * 32);
        accP = MFMA16(a, bp, accP, 0, 0, 0);
        accQ = MFMA16(a, bq, accQ, 0, 0, 0);
      }
      const int col = n0 + l15;
      if (col < DDIM) {
        float bb = bp1[col];
        for (int i = 0; i < 4; ++i) {
          int row = q * 4 + i;
          XB[row * PITCH + col] = f2bf(elu_f(accP[i] + bb));
          float pre = bf2f(preq[((size_t)t * BATCH + brow0 + row) * 600 + col]);
          Hq[row * PITCH + col] = f2bf(elu_f(accQ[i] + pre));
        }
      }
    }
    __syncthreads();

    // ---- P3: heads + sampling; waves 0-3 only
    if (wave < 4) {
      const int sel = wave >> 1, h = wave & 1;       // sel 0: prior, 1: posterior
      const unsigned short* Asrc = sel ? Hq : XB;
      const int bm = sel * 64 + h * 16;
      const int bs = bm + 32;
      floatx4 am = {0,0,0,0}, as = {0,0,0,0};
      const unsigned short* pM = ws + OFF_WHEAD + (size_t)(bm + l15) * KP + q * 8;
      const unsigned short* pS = ws + OFF_WHEAD + (size_t)(bs + l15) * KP + q * 8;
      const int aoff = l15 * PITCH + q * 8;
      for (int ki = 0; ki < 19; ++ki) {
        short8 a = *(const short8*)(&Asrc[aoff + ki * 32]);
        am = MFMA16(a, *(const short8*)(pM + ki * 32), am, 0, 0, 0);
        as = MFMA16(a, *(const short8*)(pS + ki * 32), as, 0, 0, 0);
      }
      const int c = h * 16 + l15;                    // 0..31 within S
      const float* bvec = sel ? bq2 : bp2;
      const float* epsv = sel ? eps_q : eps_p;
      const float bm_v = bvec[c], bs_v = bvec[32 + c];
      float* o_m = sel ? out_qm : out_pm;
      float* o_s = sel ? out_qs : out_ps;
      float* o_x = sel ? out_po : out_pr;
      for (int i = 0; i < 4; ++i) {
        int row = q * 4 + i;
        size_t oidx = ((size_t)t * BATCH + brow0 + row) * SDIM + c;
        float m = am[i] + bm_v;
        float sraw = as[i] + bs_v;
        float s = (sraw > 30.f ? sraw : log1pf(expf(sraw))) + 0.1f;
        float x = m + s * epsv[oidx];
        o_m[oidx] = m; o_s[oidx] = s; o_x[oidx] = x;
        if (sel) SA[row * SAPITCH + c] = f2bf(x);    // stoch carry for next step
      }
    }
    __syncthreads();
  }
}

extern "C" void kernel_launch(void* const* d_in, const int* in_sizes, int n_in,
                              void* d_out, int out_size, void* d_ws, size_t ws_size,
                              hipStream_t stream) {
  const float* enc    = (const float*)d_in[1];
  const float* act    = (const float*)d_in[2];
  const float* init_s = (const float*)d_in[3];
  const float* init_d = (const float*)d_in[4];
  const float* np_    = (const float*)d_in[5];
  const float* nq_    = (const float*)d_in[6];
  const float* Win    = (const float*)d_in[7];
  const float* b_in   = (const float*)d_in[8];
  const float* Wih    = (const float*)d_in[9];
  const float* Whh    = (const float*)d_in[10];
  const float* bih    = (const float*)d_in[11];
  const float* bhh    = (const float*)d_in[12];
  const float* Wp1    = (const float*)d_in[13];
  const float* bp1    = (const float*)d_in[14];
  const float* Wp2    = (const float*)d_in[15];
  const float* bp2    = (const float*)d_in[16];
  const float* Wq1    = (const float*)d_in[17];
  const float* bq1    = (const float*)d_in[18];
  const float* Wq2    = (const float*)d_in[19];
  const float* bq2    = (const float*)d_in[20];
  unsigned short* ws  = (unsigned short*)d_ws;
  float* out = (float*)d_out;

  stage_weights<<<dim3(256, 11), 256, 0, stream>>>(Win, Wih, Whh, Wp1, Wq1, Wp2, Wq2, ws);
  preq_gemm<<<3200, 256, 0, stream>>>(enc, bq1, ws, ws + OFF_PREQ);
  rssm_rollout<<<64, 1024, 0, stream>>>(act, init_s, init_d, np_, nq_,
                                        b_in, bih, bhh, bp1, bp2, bq2, ws, out);
}